// Round 4
// baseline (148.107 us; speedup 1.0000x reference)
//
#include <hip/hip_runtime.h>

// Problem constants (match reference)
constexpr int B        = 65536;
constexpr int N_SPARSE = 20;
constexpr int N_VARLEN = 3;
constexpr int SEQ_LEN  = 50;
constexpr int VOCAB    = 100000;
constexpr int N_DENSE  = 13;
constexpr int VAR_TOT  = N_VARLEN * SEQ_LEN;  // 150

typedef int   v4i __attribute__((ext_vector_type(4)));
typedef float v2f __attribute__((ext_vector_type(2)));

// One fused kernel. 16 lanes per row PAIR (rows 2g, 2g+1) so every stream
// load is naturally aligned: varlen pair = 75 x int4 (1200 B, 16B-aligned),
// sparse pair = 10 x int4, dense pair = 13 x float2, out = 1 x float2 store.
//
// All streaming traffic (ids, dense_x, out) is NON-TEMPORAL so it does not
// evict the 1.2 MB varlen tables from the 4 MiB per-XCD L2 — the 9.8M varlen
// gathers (88% of all gathers) must stay L2-resident. Sparse-table gathers
// (8 MB working set, can't be L2-resident) are also nt so they don't pollute.
// Tail chunks use clamped indices + zero-masked contributions (no branches),
// so each lane issues its full gather batch back-to-back.
__global__ __launch_bounds__(256) void logit_kernel(
    const int*   __restrict__ sparse_ids,    // [B, 20]
    const int*   __restrict__ varlen_ids,    // [B, 3, 50]
    const float* __restrict__ dense_x,       // [B, 13]
    const float* __restrict__ sparse_tables, // [20, VOCAB]
    const float* __restrict__ varlen_tables, // [3, VOCAB]
    const float* __restrict__ dense_w,       // [13]
    float*       __restrict__ out)           // [B]
{
    const int tid = blockIdx.x * blockDim.x + threadIdx.x;
    const int g   = tid >> 4;     // row-pair index, 0 .. B/2-1
    const int t   = tid & 15;     // lane within pair-group

    const v4i* vptr = (const v4i*)varlen_ids + (long)g * 75;
    const v4i* sptr = (const v4i*)sparse_ids + (long)g * 10;
    const v2f* dptr = (const v2f*)dense_x    + (long)g * 13;

    // ---- issue ALL streaming loads first (independent, non-temporal) ----
    v4i vid[5];
    #pragma unroll
    for (int k = 0; k < 4; ++k)
        vid[k] = __builtin_nontemporal_load(vptr + (t + 16 * k));   // chunks 0..63
    vid[4] = __builtin_nontemporal_load(vptr + (t > 10 ? 74 : t + 64)); // 64..74 (clamped dup)
    const v4i sid = __builtin_nontemporal_load(sptr + (t > 9 ? 9 : t)); // 10 chunks (clamped)
    const v2f dx  = __builtin_nontemporal_load(dptr + (t > 12 ? 12 : t)); // 13 chunks (clamped)

    float acc0 = 0.f, acc1 = 0.f;   // rows 2g, 2g+1

    // ---- varlen gathers: chunk c covers pair-positions s = 4c .. 4c+3 ----
    #pragma unroll
    for (int k = 0; k < 5; ++k) {
        const int c = (k == 4) ? (t + 64) : (t + 16 * k);  // true chunk idx (>=75 => masked)
        #pragma unroll
        for (int j = 0; j < 4; ++j) {
            const int s   = 4 * c + j;                     // pair-position (0..319)
            const bool ok = (s < 2 * VAR_TOT);
            const bool r1 = (s >= VAR_TOT);
            int p = r1 ? (s - VAR_TOT) : s;                // position within its row
            p = (p > VAR_TOT - 1) ? (VAR_TOT - 1) : p;     // keep table idx safe for !ok
            const int v  = (p >= 100) ? 2 : (p >= 50 ? 1 : 0);
            const int id = vid[k][j];
            const float val = varlen_tables[v * VOCAB + id];   // normal load: keep in L2
            const float m   = (ok && id != 0) ? val : 0.f;
            acc0 += r1 ? 0.f : m;
            acc1 += r1 ? m   : 0.f;
        }
    }

    // ---- sparse gathers: chunk t covers s = 4t .. 4t+3 (valid t < 10) ----
    {
        const int c   = (t > 9) ? 9 : t;
        const bool ok = (t < 10);
        #pragma unroll
        for (int j = 0; j < 4; ++j) {
            const int s   = 4 * c + j;                     // 0..39
            const bool r1 = (s >= N_SPARSE);
            const int f   = r1 ? (s - N_SPARSE) : s;
            const int id  = sid[j];
            const float val = __builtin_nontemporal_load(sparse_tables + f * VOCAB + id);
            const float m   = ok ? val : 0.f;
            acc0 += r1 ? 0.f : m;
            acc1 += r1 ? m   : 0.f;
        }
    }

    // ---- dense: chunk t covers s = 2t, 2t+1 (valid t < 13) ----
    {
        const int c   = (t > 12) ? 12 : t;
        const bool ok = (t < 13);
        #pragma unroll
        for (int j = 0; j < 2; ++j) {
            const int s   = 2 * c + j;                     // 0..25
            const bool r1 = (s >= N_DENSE);
            const int d   = r1 ? (s - N_DENSE) : s;
            const float prod = dx[j] * dense_w[d];
            const float m    = ok ? prod : 0.f;
            acc0 += r1 ? 0.f : m;
            acc1 += r1 ? m   : 0.f;
        }
    }

    // ---- reduce across the 16-lane group, one float2 store per pair ----
    #pragma unroll
    for (int o = 1; o < 16; o <<= 1) {
        acc0 += __shfl_xor(acc0, o);
        acc1 += __shfl_xor(acc1, o);
    }
    if (t == 0) {
        v2f r = { acc0, acc1 };
        __builtin_nontemporal_store(r, (v2f*)out + g);
    }
}

extern "C" void kernel_launch(void* const* d_in, const int* in_sizes, int n_in,
                              void* d_out, int out_size, void* d_ws, size_t ws_size,
                              hipStream_t stream) {
    const int*   sparse_ids    = (const int*)d_in[0];
    const int*   varlen_ids    = (const int*)d_in[1];
    const float* dense_x       = (const float*)d_in[2];
    const float* sparse_tables = (const float*)d_in[3];
    const float* varlen_tables = (const float*)d_in[4];
    const float* dense_w       = (const float*)d_in[5];
    float*       out           = (float*)d_out;

    const int threads = 256;
    const int total   = (B / 2) * 16;          // 16 lanes per row-pair
    const int blocks  = total / threads;       // 2048
    logit_kernel<<<blocks, threads, 0, stream>>>(
        sparse_ids, varlen_ids, dense_x, sparse_tables, varlen_tables, dense_w, out);
}

// Round 5
// 144.286 us; speedup vs baseline: 1.0265x; 1.0265x over previous
//
#include <hip/hip_runtime.h>

// Problem constants (match reference)
constexpr int B        = 65536;
constexpr int N_SPARSE = 20;
constexpr int N_VARLEN = 3;
constexpr int SEQ_LEN  = 50;
constexpr int VOCAB    = 100000;
constexpr int N_DENSE  = 13;
constexpr int VAR_TOT  = N_VARLEN * SEQ_LEN;  // 150

typedef int   v4i __attribute__((ext_vector_type(4)));
typedef float v2f __attribute__((ext_vector_type(2)));

// 16 lanes per row PAIR (rows 2g, 2g+1); every stream load naturally aligned.
// Strategy this round: MAXIMIZE memory-level parallelism. All ~26 per-lane
// loads (ids, then table gathers) are issued into register arrays before any
// summation, so the compiler can keep every gather in flight (VGPR budget
// deliberately spent on in-flight load destinations).
// Table gathers use NORMAL cached loads (R3 showed nt on gathers re-fetches
// lines: +30 MB). nt only on never-reused streams (ids, dense_x) and store.
__global__ __launch_bounds__(256) void logit_kernel(
    const int*   __restrict__ sparse_ids,    // [B, 20]
    const int*   __restrict__ varlen_ids,    // [B, 3, 50]
    const float* __restrict__ dense_x,       // [B, 13]
    const float* __restrict__ sparse_tables, // [20, VOCAB]
    const float* __restrict__ varlen_tables, // [3, VOCAB]
    const float* __restrict__ dense_w,       // [13]
    float*       __restrict__ out)           // [B]
{
    const int tid = blockIdx.x * blockDim.x + threadIdx.x;
    const int g   = tid >> 4;     // row-pair index, 0 .. B/2-1
    const int t   = tid & 15;     // lane within pair-group

    const v4i* vptr = (const v4i*)varlen_ids + (long)g * 75;
    const v4i* sptr = (const v4i*)sparse_ids + (long)g * 10;
    const v2f* dptr = (const v2f*)dense_x    + (long)g * 13;

    // ---- stage 1: issue ALL id / dense stream loads (non-temporal) ----
    v4i vid[5];
    #pragma unroll
    for (int k = 0; k < 4; ++k)
        vid[k] = __builtin_nontemporal_load(vptr + (t + 16 * k));       // chunks 0..63
    vid[4] = __builtin_nontemporal_load(vptr + (t > 10 ? 74 : t + 64)); // 64..74 (clamped)
    const v4i sid = __builtin_nontemporal_load(sptr + (t > 9 ? 9 : t));   // clamped
    const v2f dx  = __builtin_nontemporal_load(dptr + (t > 12 ? 12 : t)); // clamped

    // ---- stage 2: issue ALL table gathers into register arrays ----
    float vval[20];
    #pragma unroll
    for (int k = 0; k < 5; ++k) {
        const int c = (k == 4) ? (t + 64) : (t + 16 * k);   // true chunk (>=75 masked later)
        #pragma unroll
        for (int j = 0; j < 4; ++j) {
            const int s = 4 * c + j;                        // pair-position
            int p = (s >= VAR_TOT) ? (s - VAR_TOT) : s;
            p = (p > VAR_TOT - 1) ? (VAR_TOT - 1) : p;      // safe for masked lanes
            const int v = (p >= 100) ? 2 : (p >= 50 ? 1 : 0);
            vval[4 * k + j] = varlen_tables[v * VOCAB + vid[k][j]];  // cached load
        }
    }
    float sval[4];
    {
        const int c = (t > 9) ? 9 : t;
        #pragma unroll
        for (int j = 0; j < 4; ++j) {
            const int s = 4 * c + j;
            const int f = (s >= N_SPARSE) ? (s - N_SPARSE) : s;
            sval[j] = sparse_tables[f * VOCAB + sid[j]];             // cached load
        }
    }

    // ---- stage 3: masked accumulation (values already in flight/regs) ----
    float acc0 = 0.f, acc1 = 0.f;   // rows 2g, 2g+1

    #pragma unroll
    for (int k = 0; k < 5; ++k) {
        const int c = (k == 4) ? (t + 64) : (t + 16 * k);
        #pragma unroll
        for (int j = 0; j < 4; ++j) {
            const int s   = 4 * c + j;
            const bool ok = (s < 2 * VAR_TOT);
            const bool r1 = (s >= VAR_TOT);
            const float m = (ok && vid[k][j] != 0) ? vval[4 * k + j] : 0.f;
            acc0 += r1 ? 0.f : m;
            acc1 += r1 ? m   : 0.f;
        }
    }
    {
        const int c   = (t > 9) ? 9 : t;
        const bool ok = (t < 10);
        #pragma unroll
        for (int j = 0; j < 4; ++j) {
            const int s   = 4 * c + j;
            const bool r1 = (s >= N_SPARSE);
            const float m = ok ? sval[j] : 0.f;
            acc0 += r1 ? 0.f : m;
            acc1 += r1 ? m   : 0.f;
        }
    }
    {
        const int c   = (t > 12) ? 12 : t;
        const bool ok = (t < 13);
        #pragma unroll
        for (int j = 0; j < 2; ++j) {
            const int s   = 2 * c + j;
            const bool r1 = (s >= N_DENSE);
            const int d   = r1 ? (s - N_DENSE) : s;
            const float m = ok ? dx[j] * dense_w[d] : 0.f;
            acc0 += r1 ? 0.f : m;
            acc1 += r1 ? m   : 0.f;
        }
    }

    // ---- reduce across the 16-lane group, one float2 store per pair ----
    #pragma unroll
    for (int o = 1; o < 16; o <<= 1) {
        acc0 += __shfl_xor(acc0, o);
        acc1 += __shfl_xor(acc1, o);
    }
    if (t == 0) {
        v2f r = { acc0, acc1 };
        __builtin_nontemporal_store(r, (v2f*)out + g);
    }
}

extern "C" void kernel_launch(void* const* d_in, const int* in_sizes, int n_in,
                              void* d_out, int out_size, void* d_ws, size_t ws_size,
                              hipStream_t stream) {
    const int*   sparse_ids    = (const int*)d_in[0];
    const int*   varlen_ids    = (const int*)d_in[1];
    const float* dense_x       = (const float*)d_in[2];
    const float* sparse_tables = (const float*)d_in[3];
    const float* varlen_tables = (const float*)d_in[4];
    const float* dense_w       = (const float*)d_in[5];
    float*       out           = (float*)d_out;

    const int threads = 256;
    const int total   = (B / 2) * 16;          // 16 lanes per row-pair
    const int blocks  = total / threads;       // 2048
    logit_kernel<<<blocks, threads, 0, stream>>>(
        sparse_ids, varlen_ids, dense_x, sparse_tables, varlen_tables, dense_w, out);
}